// Round 3
// baseline (34.881 us; speedup 1.0000x reference)
//
#include <hip/hip_runtime.h>

// BinaryPositionEmbedding: out[t, :] = sum over set bits i of x[t] of w[i, :]
// x: (4, 8192) int32 -> 32768 tokens; w: (13, 1024) f32; out: (4,8192,1024) f32
//
// R2 was VALU-bound: 13 FMA/element = ~27.5 us of VALU issue per CU vs 21 us
// of write time. Fix: decompose pos = lo(7b) | hi(6b)<<7 and precompute
//   T_lo[128][1024], T_hi[64][1024]  (768 KB, L2-resident, built into d_ws)
// so the main kernel is out[t] = T_lo[lo] + T_hi[hi]: 2 L2-hit loads + 1 add
// + 1 nontemporal store per float4. nt stores keep tables resident in L2.

#define NBITS 13
#define DMOD 1024
#define LO_BITS 7
#define LO_ROWS 128            // 1 << LO_BITS
#define HI_ROWS 64             // 1 << (NBITS - LO_BITS)
#define TBL_ROWS (LO_ROWS + HI_ROWS)
#define TOK_PER_BLOCK 16

typedef float f32x4 __attribute__((ext_vector_type(4)));

// ---- Kernel A: build the two partial-sum tables in workspace ----
__global__ __launch_bounds__(256) void bpe_build_tables(
    const float* __restrict__ w, float* __restrict__ tbl) {
    const int r = blockIdx.x;              // 0..191
    const int d0 = threadIdx.x * 4;
    int v, nb, b0;
    if (r < LO_ROWS) { v = r;            nb = LO_BITS;          b0 = 0; }
    else             { v = r - LO_ROWS;  nb = NBITS - LO_BITS;  b0 = LO_BITS; }

    f32x4 s = {0.f, 0.f, 0.f, 0.f};
    for (int i = 0; i < nb; ++i) {
        if ((v >> i) & 1) {
            const f32x4 wi = *reinterpret_cast<const f32x4*>(&w[(b0 + i) * DMOD + d0]);
            s.x += wi.x; s.y += wi.y; s.z += wi.z; s.w += wi.w;
        }
    }
    *reinterpret_cast<f32x4*>(&tbl[(size_t)r * DMOD + d0]) = s;
}

// ---- Kernel B: out[tok] = T_lo[pos & 127] + T_hi[pos >> 7] ----
__global__ __launch_bounds__(256) void bpe_gather_add(
    const int* __restrict__ x, const float* __restrict__ tbl,
    float* __restrict__ out, int n_tokens) {
    const int d0 = threadIdx.x * 4;
    const float* __restrict__ tlo = tbl;
    const float* __restrict__ thi = tbl + (size_t)LO_ROWS * DMOD;

    const int tok0 = blockIdx.x * TOK_PER_BLOCK;
    const bool full = (tok0 + TOK_PER_BLOCK) <= n_tokens;

    if (full) {
#pragma unroll
        for (int k = 0; k < TOK_PER_BLOCK; ++k) {
            const int tok = tok0 + k;
            const int pos = x[tok];                    // block-uniform -> s_load
            const f32x4 a = *reinterpret_cast<const f32x4*>(&tlo[(size_t)(pos & (LO_ROWS - 1)) * DMOD + d0]);
            const f32x4 b = *reinterpret_cast<const f32x4*>(&thi[(size_t)(pos >> LO_BITS) * DMOD + d0]);
            f32x4 s;
            s.x = a.x + b.x; s.y = a.y + b.y; s.z = a.z + b.z; s.w = a.w + b.w;
            f32x4* dst = reinterpret_cast<f32x4*>(&out[(size_t)tok * DMOD + d0]);
            __builtin_nontemporal_store(s, dst);
        }
    } else {
        for (int k = 0; k < TOK_PER_BLOCK; ++k) {
            const int tok = tok0 + k;
            if (tok >= n_tokens) break;
            const int pos = x[tok];
            const f32x4 a = *reinterpret_cast<const f32x4*>(&tlo[(size_t)(pos & (LO_ROWS - 1)) * DMOD + d0]);
            const f32x4 b = *reinterpret_cast<const f32x4*>(&thi[(size_t)(pos >> LO_BITS) * DMOD + d0]);
            f32x4 s;
            s.x = a.x + b.x; s.y = a.y + b.y; s.z = a.z + b.z; s.w = a.w + b.w;
            f32x4* dst = reinterpret_cast<f32x4*>(&out[(size_t)tok * DMOD + d0]);
            __builtin_nontemporal_store(s, dst);
        }
    }
}

// ---- Fallback (R2 kernel) if workspace is too small for the tables ----
__global__ __launch_bounds__(256) void bpe_direct(
    const int* __restrict__ x, const float* __restrict__ w,
    float* __restrict__ out, int n_tokens) {
    const int d0 = threadIdx.x * 4;
    f32x4 wr[NBITS];
#pragma unroll
    for (int i = 0; i < NBITS; ++i)
        wr[i] = *reinterpret_cast<const f32x4*>(&w[i * DMOD + d0]);

    const int tok0 = blockIdx.x * TOK_PER_BLOCK;
#pragma unroll
    for (int k = 0; k < TOK_PER_BLOCK; ++k) {
        const int tok = tok0 + k;
        if (tok >= n_tokens) break;
        const int pos = x[tok];
        f32x4 s = {0.f, 0.f, 0.f, 0.f};
#pragma unroll
        for (int i = 0; i < NBITS; ++i) {
            const float b = (float)((pos >> i) & 1);
            s.x = fmaf(b, wr[i].x, s.x);
            s.y = fmaf(b, wr[i].y, s.y);
            s.z = fmaf(b, wr[i].z, s.z);
            s.w = fmaf(b, wr[i].w, s.w);
        }
        f32x4* dst = reinterpret_cast<f32x4*>(&out[(size_t)tok * DMOD + d0]);
        __builtin_nontemporal_store(s, dst);
    }
}

extern "C" void kernel_launch(void* const* d_in, const int* in_sizes, int n_in,
                              void* d_out, int out_size, void* d_ws, size_t ws_size,
                              hipStream_t stream) {
    const int* x = (const int*)d_in[0];     // 32768 int32 positions
    const float* w = (const float*)d_in[1]; // 13 x 1024 f32
    float* out = (float*)d_out;             // 32768 x 1024 f32

    const int n_tokens = in_sizes[0];
    const int blocks = (n_tokens + TOK_PER_BLOCK - 1) / TOK_PER_BLOCK;
    const size_t tbl_bytes = (size_t)TBL_ROWS * DMOD * sizeof(float);  // 768 KB

    if (ws_size >= tbl_bytes) {
        float* tbl = (float*)d_ws;
        bpe_build_tables<<<TBL_ROWS, 256, 0, stream>>>(w, tbl);
        bpe_gather_add<<<blocks, 256, 0, stream>>>(x, tbl, out, n_tokens);
    } else {
        bpe_direct<<<blocks, 256, 0, stream>>>(x, w, out, n_tokens);
    }
}

// Round 4
// 31.526 us; speedup vs baseline: 1.1064x; 1.1064x over previous
//
#include <hip/hip_runtime.h>

// BinaryPositionEmbedding: out[t, :] = sum over set bits i of x[t] of w[i, :]
// x: (4, 8192) int32 -> 32768 tokens; w: (13, 1024) f32; out: (4,8192,1024) f32
//
// R2 (direct FMA) and R3 (L2 table gather) both hit 34.8 us => shared
// bottleneck is the store stream, which both forced to HBM via nontemporal
// stores (3.86 TB/s effective). Output is 128 MiB < 256 MiB Infinity Cache:
// use NORMAL stores so L2/L3 absorb the write stream. Keep the table
// decomposition (pos = lo7 | hi6<<7, T_lo[128][1024] + T_hi[64][1024] in
// d_ws, 768 KB, L2-resident) so VALU stays ~8 us and cannot become the limit.

#define NBITS 13
#define DMOD 1024
#define LO_BITS 7
#define LO_ROWS 128            // 1 << LO_BITS
#define HI_ROWS 64             // 1 << (NBITS - LO_BITS)
#define TBL_ROWS (LO_ROWS + HI_ROWS)
#define TOK_PER_BLOCK 16

typedef float f32x4 __attribute__((ext_vector_type(4)));

// ---- Kernel A: build the two partial-sum tables in workspace ----
__global__ __launch_bounds__(256) void bpe_build_tables(
    const float* __restrict__ w, float* __restrict__ tbl) {
    const int r = blockIdx.x;              // 0..191
    const int d0 = threadIdx.x * 4;
    int v, nb, b0;
    if (r < LO_ROWS) { v = r;            nb = LO_BITS;          b0 = 0; }
    else             { v = r - LO_ROWS;  nb = NBITS - LO_BITS;  b0 = LO_BITS; }

    f32x4 s = {0.f, 0.f, 0.f, 0.f};
    for (int i = 0; i < nb; ++i) {
        if ((v >> i) & 1) {
            const f32x4 wi = *reinterpret_cast<const f32x4*>(&w[(b0 + i) * DMOD + d0]);
            s.x += wi.x; s.y += wi.y; s.z += wi.z; s.w += wi.w;
        }
    }
    *reinterpret_cast<f32x4*>(&tbl[(size_t)r * DMOD + d0]) = s;
}

// ---- Kernel B: out[tok] = T_lo[pos & 127] + T_hi[pos >> 7] ----
__global__ __launch_bounds__(256) void bpe_gather_add(
    const int* __restrict__ x, const float* __restrict__ tbl,
    float* __restrict__ out, int n_tokens) {
    const int d0 = threadIdx.x * 4;
    const float* __restrict__ tlo = tbl;
    const float* __restrict__ thi = tbl + (size_t)LO_ROWS * DMOD;

    const int tok0 = blockIdx.x * TOK_PER_BLOCK;
    const bool full = (tok0 + TOK_PER_BLOCK) <= n_tokens;

    if (full) {
#pragma unroll
        for (int k = 0; k < TOK_PER_BLOCK; ++k) {
            const int tok = tok0 + k;
            const int pos = x[tok];                    // block-uniform -> s_load
            const f32x4 a = *reinterpret_cast<const f32x4*>(&tlo[(size_t)(pos & (LO_ROWS - 1)) * DMOD + d0]);
            const f32x4 b = *reinterpret_cast<const f32x4*>(&thi[(size_t)(pos >> LO_BITS) * DMOD + d0]);
            f32x4 s;
            s.x = a.x + b.x; s.y = a.y + b.y; s.z = a.z + b.z; s.w = a.w + b.w;
            *reinterpret_cast<f32x4*>(&out[(size_t)tok * DMOD + d0]) = s;  // normal store: let L2/L3 absorb
        }
    } else {
        for (int k = 0; k < TOK_PER_BLOCK; ++k) {
            const int tok = tok0 + k;
            if (tok >= n_tokens) break;
            const int pos = x[tok];
            const f32x4 a = *reinterpret_cast<const f32x4*>(&tlo[(size_t)(pos & (LO_ROWS - 1)) * DMOD + d0]);
            const f32x4 b = *reinterpret_cast<const f32x4*>(&thi[(size_t)(pos >> LO_BITS) * DMOD + d0]);
            f32x4 s;
            s.x = a.x + b.x; s.y = a.y + b.y; s.z = a.z + b.z; s.w = a.w + b.w;
            *reinterpret_cast<f32x4*>(&out[(size_t)tok * DMOD + d0]) = s;
        }
    }
}

extern "C" void kernel_launch(void* const* d_in, const int* in_sizes, int n_in,
                              void* d_out, int out_size, void* d_ws, size_t ws_size,
                              hipStream_t stream) {
    const int* x = (const int*)d_in[0];     // 32768 int32 positions
    const float* w = (const float*)d_in[1]; // 13 x 1024 f32
    float* out = (float*)d_out;             // 32768 x 1024 f32

    const int n_tokens = in_sizes[0];
    const int blocks = (n_tokens + TOK_PER_BLOCK - 1) / TOK_PER_BLOCK;

    float* tbl = (float*)d_ws;              // 768 KB, ws is preallocated scratch
    bpe_build_tables<<<TBL_ROWS, 256, 0, stream>>>(w, tbl);
    bpe_gather_add<<<blocks, 256, 0, stream>>>(x, tbl, out, n_tokens);
}

// Round 5
// 28.102 us; speedup vs baseline: 1.2412x; 1.1219x over previous
//
#include <hip/hip_runtime.h>

// BinaryPositionEmbedding: out[t, :] = sum over set bits i of x[t] of w[i, :]
// x: (4, 8192) int32 -> 32768 tokens; w: (13, 1024) f32; out: (4,8192,1024) f32
//
// R4 lesson: VALU cost of the direct 13-FMA form is only ~5.5-9 us chip-wide
// (128 FMA/cyc/CU x 256 CU), far under the ~20-27 us store stream. The R3/R4
// table decomposition bought nothing and cost a dependent build kernel plus
// 268 MB of L2 table reads. Fuse back to ONE kernel: weights in registers
// (13 x f32x4 = 52 VGPR), 13 FMAs per f32x4, normal (cache-resident) stores —
// output is 128 MiB < 256 MiB L3.

#define NBITS 13
#define DMOD 1024
#define TOK_PER_BLOCK 16

typedef float f32x4 __attribute__((ext_vector_type(4)));

__global__ __launch_bounds__(256) void bpe_direct(
    const int* __restrict__ x, const float* __restrict__ w,
    float* __restrict__ out, int n_tokens) {
    const int d0 = threadIdx.x * 4;

    // This thread's slice of the weight table, kept in registers.
    f32x4 wr[NBITS];
#pragma unroll
    for (int i = 0; i < NBITS; ++i)
        wr[i] = *reinterpret_cast<const f32x4*>(&w[i * DMOD + d0]);

    const int tok0 = blockIdx.x * TOK_PER_BLOCK;
    const bool full = (tok0 + TOK_PER_BLOCK) <= n_tokens;

    if (full) {
#pragma unroll
        for (int k = 0; k < TOK_PER_BLOCK; ++k) {
            const int tok = tok0 + k;
            const int pos = x[tok];                 // block-uniform -> s_load
            f32x4 s = {0.f, 0.f, 0.f, 0.f};
#pragma unroll
            for (int i = 0; i < NBITS; ++i) {
                const float b = (float)((pos >> i) & 1);
                s.x = fmaf(b, wr[i].x, s.x);
                s.y = fmaf(b, wr[i].y, s.y);
                s.z = fmaf(b, wr[i].z, s.z);
                s.w = fmaf(b, wr[i].w, s.w);
            }
            *reinterpret_cast<f32x4*>(&out[(size_t)tok * DMOD + d0]) = s;
        }
    } else {
        for (int k = 0; k < TOK_PER_BLOCK; ++k) {
            const int tok = tok0 + k;
            if (tok >= n_tokens) break;
            const int pos = x[tok];
            f32x4 s = {0.f, 0.f, 0.f, 0.f};
#pragma unroll
            for (int i = 0; i < NBITS; ++i) {
                const float b = (float)((pos >> i) & 1);
                s.x = fmaf(b, wr[i].x, s.x);
                s.y = fmaf(b, wr[i].y, s.y);
                s.z = fmaf(b, wr[i].z, s.z);
                s.w = fmaf(b, wr[i].w, s.w);
            }
            *reinterpret_cast<f32x4*>(&out[(size_t)tok * DMOD + d0]) = s;
        }
    }
}

extern "C" void kernel_launch(void* const* d_in, const int* in_sizes, int n_in,
                              void* d_out, int out_size, void* d_ws, size_t ws_size,
                              hipStream_t stream) {
    const int* x = (const int*)d_in[0];     // 32768 int32 positions
    const float* w = (const float*)d_in[1]; // 13 x 1024 f32
    float* out = (float*)d_out;             // 32768 x 1024 f32

    const int n_tokens = in_sizes[0];
    const int blocks = (n_tokens + TOK_PER_BLOCK - 1) / TOK_PER_BLOCK;
    bpe_direct<<<blocks, 256, 0, stream>>>(x, w, out, n_tokens);
}

// Round 6
// 27.409 us; speedup vs baseline: 1.2726x; 1.0253x over previous
//
#include <hip/hip_runtime.h>

// BinaryPositionEmbedding: out[t, :] = sum over set bits i of x[t] of w[i, :]
// x: (4, 8192) int32 -> 32768 tokens; w: (13, 1024) f32; out: (4,8192,1024) f32
//
// R5: direct 1-kernel form, normal stores = 28.1 us (4.78 TB/s effective vs
// 6.8 TB/s fill ceiling -> ~19.7 us floor). R6 lever: TOK_PER_BLOCK 16->32
// (1024 blocks, 4 blocks/CU): halves per-block weight-preamble traffic
// (106->53 MB L2 reads) and per-block ramp overhead; still 16 waves/CU for
// store-queue saturation. Pointer-increment addressing (4 KB token stride
// exceeds the 13-bit store imm-offset range, so hand the compiler a simple
// add recurrence).

#define NBITS 13
#define DMOD 1024
#define TOK_PER_BLOCK 32

typedef float f32x4 __attribute__((ext_vector_type(4)));

__global__ __launch_bounds__(256) void bpe_direct(
    const int* __restrict__ x, const float* __restrict__ w,
    float* __restrict__ out, int n_tokens) {
    const int d0 = threadIdx.x * 4;

    // This thread's slice of the weight table, kept in registers (13 x f32x4).
    f32x4 wr[NBITS];
#pragma unroll
    for (int i = 0; i < NBITS; ++i)
        wr[i] = *reinterpret_cast<const f32x4*>(&w[i * DMOD + d0]);

    const int tok0 = blockIdx.x * TOK_PER_BLOCK;
    const float* dst_base = &out[(size_t)tok0 * DMOD + d0];

    if ((tok0 + TOK_PER_BLOCK) <= n_tokens) {
#pragma unroll
        for (int k = 0; k < TOK_PER_BLOCK; ++k) {
            const int pos = x[tok0 + k];            // block-uniform -> s_load
            f32x4 s = {0.f, 0.f, 0.f, 0.f};
#pragma unroll
            for (int i = 0; i < NBITS; ++i) {
                const float b = (float)((pos >> i) & 1);
                s.x = fmaf(b, wr[i].x, s.x);
                s.y = fmaf(b, wr[i].y, s.y);
                s.z = fmaf(b, wr[i].z, s.z);
                s.w = fmaf(b, wr[i].w, s.w);
            }
            *reinterpret_cast<f32x4*>(const_cast<float*>(dst_base) + (size_t)k * DMOD) = s;
        }
    } else {
        for (int k = 0; k < TOK_PER_BLOCK; ++k) {
            const int tok = tok0 + k;
            if (tok >= n_tokens) break;
            const int pos = x[tok];
            f32x4 s = {0.f, 0.f, 0.f, 0.f};
#pragma unroll
            for (int i = 0; i < NBITS; ++i) {
                const float b = (float)((pos >> i) & 1);
                s.x = fmaf(b, wr[i].x, s.x);
                s.y = fmaf(b, wr[i].y, s.y);
                s.z = fmaf(b, wr[i].z, s.z);
                s.w = fmaf(b, wr[i].w, s.w);
            }
            *reinterpret_cast<f32x4*>(const_cast<float*>(dst_base) + (size_t)k * DMOD) = s;
        }
    }
}

extern "C" void kernel_launch(void* const* d_in, const int* in_sizes, int n_in,
                              void* d_out, int out_size, void* d_ws, size_t ws_size,
                              hipStream_t stream) {
    const int* x = (const int*)d_in[0];     // 32768 int32 positions
    const float* w = (const float*)d_in[1]; // 13 x 1024 f32
    float* out = (float*)d_out;             // 32768 x 1024 f32

    const int n_tokens = in_sizes[0];
    const int blocks = (n_tokens + TOK_PER_BLOCK - 1) / TOK_PER_BLOCK;
    bpe_direct<<<blocks, 256, 0, stream>>>(x, w, out, n_tokens);
}